// Round 8
// baseline (643.758 us; speedup 1.0000x reference)
//
#include <hip/hip_runtime.h>
#include <hip/hip_bf16.h>
#include <math.h>

#define NN 8192
#define DD 512
#define INV_T 14.285714285714286f   // 1/0.07 ; also the logits_max (diagonal) value

typedef __attribute__((ext_vector_type(8))) short s16x8;  // 8 bf16 = 4 VGPRs
typedef __attribute__((ext_vector_type(4))) float f32x4;
typedef __attribute__((ext_vector_type(4))) int   i32x4;

__device__ __forceinline__ unsigned short f32_to_bf16(float f) {
  unsigned int u = __float_as_uint(f);
  u += 0x7FFFu + ((u >> 16) & 1u);   // round-to-nearest-even
  return (unsigned short)(u >> 16);
}

__device__ __forceinline__ void async16(const void* g, void* l) {
  // 16B-wide global->LDS DMA; LDS dest must be wave-uniform base + lane*16
  __builtin_amdgcn_global_load_lds((__attribute__((address_space(1))) void*)(void*)g,
                                   (__attribute__((address_space(3))) void*)l,
                                   16, 0, 0);
}

// ---------------- Kernel A: normalize rows, emit bf16 ----------------
__global__ __launch_bounds__(256) void normalize_kernel(const float* __restrict__ f,
                                                        unsigned short* __restrict__ fnb) {
  const int wave = threadIdx.x >> 6;
  const int lane = threadIdx.x & 63;
  const int row  = blockIdx.x * 4 + wave;
  const float* src = f + (size_t)row * DD + lane * 8;
  float4 v0 = *(const float4*)src;
  float4 v1 = *(const float4*)(src + 4);
  float ss = v0.x*v0.x + v0.y*v0.y + v0.z*v0.z + v0.w*v0.w
           + v1.x*v1.x + v1.y*v1.y + v1.z*v1.z + v1.w*v1.w;
  #pragma unroll
  for (int o = 32; o; o >>= 1) ss += __shfl_xor(ss, o);
  const float r = 1.0f / fmaxf(sqrtf(ss), 1e-8f);
  ushort4 a, b;
  a.x = f32_to_bf16(v0.x * r); a.y = f32_to_bf16(v0.y * r);
  a.z = f32_to_bf16(v0.z * r); a.w = f32_to_bf16(v0.w * r);
  b.x = f32_to_bf16(v1.x * r); b.y = f32_to_bf16(v1.y * r);
  b.z = f32_to_bf16(v1.z * r); b.w = f32_to_bf16(v1.w * r);
  unsigned short* dst = fnb + (size_t)row * DD + lane * 8;
  *(ushort4*)dst = a;
  *(ushort4*)(dst + 4) = b;
}

// ---------------- Kernel P: pack-v2, int4 + pipelined ----------------
// Bit convention (permuted): word w covers elements w*64..w*64+63; element
// e64 = 4*lam + c (lam=0..15, c=0..3) sits at bit (c<<4)|lam.
// Word flat index = row*128 + (col>>6).
__global__ __launch_bounds__(256) void pack_kernel(const int* __restrict__ posm,
                                                   const int* __restrict__ negm,
                                                   unsigned long long* __restrict__ pb,
                                                   unsigned long long* __restrict__ nb) {
  const int lane = threadIdx.x & 63;
  const int gw = (int)((blockIdx.x * 256 + threadIdx.x) >> 6);   // 0..8191
  const int lofs = lane * 4;

  i32x4 vp[2][4], vn[2][4];
  #pragma unroll
  for (int u = 0; u < 4; ++u) {
    const size_t b = ((size_t)gw * 4 + u) * 256 + lofs;
    vp[0][u] = __builtin_nontemporal_load((const i32x4*)(posm + b));
    vn[0][u] = __builtin_nontemporal_load((const i32x4*)(negm + b));
  }
  #pragma unroll 1
  for (int it = 0; it < 8; ++it) {
    const int cur = it & 1, nxt = cur ^ 1;
    if (it < 7) {   // issue next iteration's 8 loads before consuming current
      #pragma unroll
      for (int u = 0; u < 4; ++u) {
        const size_t b = (((size_t)(it + 1) * 8192 + gw) * 4 + u) * 256 + lofs;
        vp[nxt][u] = __builtin_nontemporal_load((const i32x4*)(posm + b));
        vn[nxt][u] = __builtin_nontemporal_load((const i32x4*)(negm + b));
      }
    }
    const long long s0 = ((long long)it * 8192 + gw) * 4;
    #pragma unroll
    for (int u = 0; u < 4; ++u) {
      {
        const i32x4 v = vp[cur][u];
        const unsigned long long bx = __ballot(v.x != 0), by = __ballot(v.y != 0),
                                 bz = __ballot(v.z != 0), bw = __ballot(v.w != 0);
        if (lane < 2) {
          const int k0 = lane * 2;
          ulonglong2 t;
          t.x = ((bx >> (16*k0)) & 0xFFFFull)        | (((by >> (16*k0)) & 0xFFFFull) << 16)
              | (((bz >> (16*k0)) & 0xFFFFull) << 32) | (((bw >> (16*k0)) & 0xFFFFull) << 48);
          t.y = ((bx >> (16*k0+16)) & 0xFFFFull)        | (((by >> (16*k0+16)) & 0xFFFFull) << 16)
              | (((bz >> (16*k0+16)) & 0xFFFFull) << 32) | (((bw >> (16*k0+16)) & 0xFFFFull) << 48);
          *(ulonglong2*)(pb + (s0 + u) * 4 + k0) = t;
        }
      }
      {
        const i32x4 v = vn[cur][u];
        const unsigned long long bx = __ballot(v.x != 0), by = __ballot(v.y != 0),
                                 bz = __ballot(v.z != 0), bw = __ballot(v.w != 0);
        if (lane < 2) {
          const int k0 = lane * 2;
          ulonglong2 t;
          t.x = ((bx >> (16*k0)) & 0xFFFFull)        | (((by >> (16*k0)) & 0xFFFFull) << 16)
              | (((bz >> (16*k0)) & 0xFFFFull) << 32) | (((bw >> (16*k0)) & 0xFFFFull) << 48);
          t.y = ((bx >> (16*k0+16)) & 0xFFFFull)        | (((by >> (16*k0+16)) & 0xFFFFull) << 16)
              | (((bz >> (16*k0+16)) & 0xFFFFull) << 32) | (((bw >> (16*k0+16)) & 0xFFFFull) << 48);
          *(ulonglong2*)(nb + (s0 + u) * 4 + k0) = t;
        }
      }
    }
  }
}

// ---------------- Kernel B: fused-v2 -- LDS GEMM + bit epilogue + LDS accum ----------------
__global__ __launch_bounds__(256, 3) void fused_kernel(const unsigned short* __restrict__ fnb,
                                                       const unsigned long long* __restrict__ pb,
                                                       const unsigned long long* __restrict__ nb,
                                                       float* __restrict__ Spos,
                                                       float* __restrict__ Sneg,
                                                       float* __restrict__ Pcnt) {
  // decode compact triangular block id -> (bi, bj), bi <= bj, 64x64 block grid
  const int bid = blockIdx.x;
  int bi = (int)(64.5 - sqrt(64.5 * 64.5 - 2.0 * (double)bid));
  while (64 * bi - bi * (bi - 1) / 2 > bid) --bi;
  while (64 * (bi + 1) - (bi + 1) * bi / 2 <= bid) ++bi;
  const int bj = bi + (bid - (64 * bi - bi * (bi - 1) / 2));
  const int I = bi * 128;
  const int J = bj * 128;
  const bool offdiag = (bi != bj);

  const int tid  = threadIdx.x;
  const int wave = tid >> 6;
  const int lane = tid & 63;
  const int wm = wave >> 1;            // 0..1 row half
  const int wn = wave & 1;             // 0..1 col half
  const int q   = lane >> 4;           // 0..3
  const int c16 = lane & 15;           // 0..15

  __shared__ alignas(16) unsigned short lA[128 * 32];
  __shared__ alignas(16) unsigned short lB[128 * 32];
  __shared__ float sacc[2][128][3];    // [panel][row][Spos,Sneg,Pcnt]
  for (int t = tid; t < 2 * 128 * 3; t += 256) ((float*)sacc)[t] = 0.f;

  // ---- GEMM: coalesced async16 staging, XOR-swizzled LDS (R2-proven) ----
  f32x4 acc[4][4];
  const f32x4 z4 = {0.f, 0.f, 0.f, 0.f};
  #pragma unroll
  for (int mt = 0; mt < 4; ++mt)
    #pragma unroll
    for (int nt = 0; nt < 4; ++nt) acc[mt][nt] = z4;

  for (int kk = 0; kk < DD / 32; ++kk) {
    const int k0 = kk * 32;
    #pragma unroll
    for (int c = 0; c < 2; ++c) {
      const int fidx = tid + c * 256;        // 0..511 16B-chunks
      const int row  = fidx >> 2;
      const int p    = fidx & 3;
      const int csrc = (p ^ ((row >> 1) & 3)) & 3;   // XOR swizzle (global side only)
      async16(fnb + (size_t)(I + row) * DD + k0 + csrc * 8, (char*)lA + fidx * 16);
      async16(fnb + (size_t)(J + row) * DD + k0 + csrc * 8, (char*)lB + fidx * 16);
    }
    __syncthreads();

    s16x8 aF[4], bF[4];
    #pragma unroll
    for (int t = 0; t < 4; ++t) {
      const int arow = wm * 64 + t * 16 + c16;
      const int apos = (q ^ ((arow >> 1) & 3)) & 3;
      aF[t] = *(const s16x8*)((const char*)lA + arow * 64 + apos * 16);
      const int brow = wn * 64 + t * 16 + c16;
      const int bpos = (q ^ ((brow >> 1) & 3)) & 3;
      bF[t] = *(const s16x8*)((const char*)lB + brow * 64 + bpos * 16);
    }
    #pragma unroll
    for (int mt = 0; mt < 4; ++mt)
      #pragma unroll
      for (int nt = 0; nt < 4; ++nt)
        acc[mt][nt] = __builtin_amdgcn_mfma_f32_16x16x32_bf16(aF[mt], bF[nt], acc[mt][nt], 0, 0, 0);
    __syncthreads();
  }

  // ---- epilogue ----
  // acc[mt][nt][r] = sim[I + wm*64 + mt*16 + q*4 + r][J + wn*64 + nt*16 + c16]
  const bool hasdiag = (bi == bj) && (wm == wn);

  // issue all bit-word loads first (tiny, L2/L3-hot)
  unsigned long long dpw[4][4], dnw[4][4];   // direct: [mt][r], word bj*2+wn of row I+..
  #pragma unroll
  for (int mt = 0; mt < 4; ++mt)
    #pragma unroll
    for (int r = 0; r < 4; ++r) {
      const size_t a = (size_t)(I + wm * 64 + mt * 16 + q * 4 + r) * 128 + bj * 2 + wn;
      dpw[mt][r] = pb[a];
      dnw[mt][r] = nb[a];
    }
  unsigned long long tpw[4], tnw[4];         // transposed: [nt], word bi*2+wm of row J+cl
  if (offdiag) {
    #pragma unroll
    for (int nt = 0; nt < 4; ++nt) {
      const size_t a = (size_t)(J + wn * 64 + nt * 16 + c16) * 128 + bi * 2 + wm;
      tpw[nt] = pb[a];
      tnw[nt] = nb[a];
    }
  }

  #pragma unroll
  for (int mt = 0; mt < 4; ++mt)
    #pragma unroll
    for (int nt = 0; nt < 4; ++nt)
      #pragma unroll
      for (int r = 0; r < 4; ++r)
        acc[mt][nt][r] = __expf(acc[mt][nt][r] * INV_T - INV_T);

  // direct pass: bit of col (nt*16+c16) = (nt*4 + (c16>>2)) | ((c16&3)<<4)
  const int shd = (c16 >> 2) + (c16 & 3) * 16;
  #pragma unroll
  for (int mt = 0; mt < 4; ++mt) {
    const int rl = wm * 64 + mt * 16 + q * 4;
    #pragma unroll
    for (int r = 0; r < 4; ++r) {
      unsigned long long wp = dpw[mt][r], wnn = dnw[mt][r];
      if (hasdiag) {   // clear this row's own diagonal bit: col64 = mt*16+q*4+r
        const unsigned long long m = ~(1ULL << (mt * 4 + q + 16 * r));
        wp &= m; wnn &= m;
      }
      float dsp = 0.f, dsn = 0.f;
      #pragma unroll
      for (int nt = 0; nt < 4; ++nt) {
        const float e = acc[mt][nt][r];
        dsp = fmaf(e, (float)((wp  >> (nt * 4 + shd)) & 1ULL), dsp);
        dsn = fmaf(e, (float)((wnn >> (nt * 4 + shd)) & 1ULL), dsn);
      }
      #pragma unroll
      for (int o = 1; o <= 8; o <<= 1) {
        dsp += __shfl_xor(dsp, o);
        dsn += __shfl_xor(dsn, o);
      }
      if (c16 == 0) {
        atomicAdd(&sacc[0][rl + r][0], dsp);
        atomicAdd(&sacc[0][rl + r][1], dsn);
        atomicAdd(&sacc[0][rl + r][2], (float)__popcll(wp));
      }
    }
  }

  // transposed pass: bit of col (mt*16+q*4+r) = (mt*4+q) | (r<<4)
  if (offdiag) {
    #pragma unroll
    for (int nt = 0; nt < 4; ++nt) {
      const int cl = wn * 64 + nt * 16 + c16;
      float ts = 0.f, tn = 0.f;
      #pragma unroll
      for (int mt = 0; mt < 4; ++mt) {
        const int sh = mt * 4 + q;
        #pragma unroll
        for (int r = 0; r < 4; ++r) {
          const float e = acc[mt][nt][r];
          ts = fmaf(e, (float)((tpw[nt] >> (sh + 16 * r)) & 1ULL), ts);
          tn = fmaf(e, (float)((tnw[nt] >> (sh + 16 * r)) & 1ULL), tn);
        }
      }
      ts += __shfl_xor(ts, 16); ts += __shfl_xor(ts, 32);
      tn += __shfl_xor(tn, 16); tn += __shfl_xor(tn, 32);
      if (q == 0) {
        atomicAdd(&sacc[1][cl][0], ts);
        atomicAdd(&sacc[1][cl][1], tn);
        atomicAdd(&sacc[1][cl][2], (float)__popcll(tpw[nt]));
      }
    }
  }

  __syncthreads();

  // one batch of global atomics at the very end
  const int r = tid & 127;
  if (tid < 128) {
    atomicAdd(&Spos[I + r], sacc[0][r][0]);
    atomicAdd(&Sneg[I + r], sacc[0][r][1]);
    atomicAdd(&Pcnt[I + r], sacc[0][r][2]);
  } else if (offdiag) {
    atomicAdd(&Spos[J + r], sacc[1][r][0]);
    atomicAdd(&Sneg[J + r], sacc[1][r][1]);
    atomicAdd(&Pcnt[J + r], sacc[1][r][2]);
  }
}

// ---------------- Kernel C: finalize ----------------
__global__ __launch_bounds__(256) void finalize_kernel(const float* __restrict__ Spos,
                                                       const float* __restrict__ Sneg,
                                                       const float* __restrict__ Pcnt,
                                                       float* __restrict__ out) {
  float local = 0.f;
  for (int i = threadIdx.x; i < NN; i += 256) {
    const float sp = Spos[i], sn = Sneg[i], pc = Pcnt[i];
    const float card = (pc == 0.f) ? 1.f : pc;
    local += (logf(sn) * pc - sp) / card;
  }
  #pragma unroll
  for (int o = 32; o; o >>= 1) local += __shfl_xor(local, o);
  __shared__ float red[4];
  if ((threadIdx.x & 63) == 0) red[threadIdx.x >> 6] = local;
  __syncthreads();
  if (threadIdx.x == 0)
    out[0] = (red[0] + red[1] + red[2] + red[3]) * (1.0f / (float)NN);
}

extern "C" void kernel_launch(void* const* d_in, const int* in_sizes, int n_in,
                              void* d_out, int out_size, void* d_ws, size_t ws_size,
                              hipStream_t stream) {
  const float* feat = (const float*)d_in[0];
  const int* posm   = (const int*)d_in[1];
  const int* negm   = (const int*)d_in[2];
  float* out = (float*)d_out;

  char* ws = (char*)d_ws;
  unsigned short* fnb = (unsigned short*)ws;                                        // 8 MB
  unsigned long long* pbit = (unsigned long long*)(ws + (size_t)8 * 1024 * 1024);   // 8 MB
  unsigned long long* nbit = (unsigned long long*)(ws + (size_t)16 * 1024 * 1024);  // 8 MB
  float* Spos = (float*)(ws + (size_t)24 * 1024 * 1024);
  float* Sneg = Spos + NN;
  float* Pcnt = Sneg + NN;

  hipMemsetAsync(Spos, 0, 3 * NN * sizeof(float), stream);
  normalize_kernel<<<NN / 4, 256, 0, stream>>>(feat, fnb);
  pack_kernel<<<2048, 256, 0, stream>>>(posm, negm, pbit, nbit);
  fused_kernel<<<2080, 256, 0, stream>>>(fnb, pbit, nbit, Spos, Sneg, Pcnt);
  finalize_kernel<<<1, 256, 0, stream>>>(Spos, Sneg, Pcnt, out);
}

// Round 9
// 548.590 us; speedup vs baseline: 1.1735x; 1.1735x over previous
//
#include <hip/hip_runtime.h>
#include <hip/hip_bf16.h>
#include <math.h>

#define NN 8192
#define DD 512
#define INV_T 14.285714285714286f   // 1/0.07 ; also the logits_max (diagonal) value

typedef __attribute__((ext_vector_type(8))) short s16x8;  // 8 bf16 = 4 VGPRs
typedef __attribute__((ext_vector_type(4))) float f32x4;
typedef __attribute__((ext_vector_type(4))) int   i32x4;

__device__ __forceinline__ unsigned short f32_to_bf16(float f) {
  unsigned int u = __float_as_uint(f);
  u += 0x7FFFu + ((u >> 16) & 1u);   // round-to-nearest-even
  return (unsigned short)(u >> 16);
}

__device__ __forceinline__ void async16(const void* g, void* l) {
  // 16B-wide global->LDS DMA; LDS dest must be wave-uniform base + lane*16
  __builtin_amdgcn_global_load_lds((__attribute__((address_space(1))) void*)(void*)g,
                                   (__attribute__((address_space(3))) void*)l,
                                   16, 0, 0);
}

// ---------------- Kernel A: normalize rows, emit bf16 ----------------
__global__ __launch_bounds__(256) void normalize_kernel(const float* __restrict__ f,
                                                        unsigned short* __restrict__ fnb) {
  const int wave = threadIdx.x >> 6;
  const int lane = threadIdx.x & 63;
  const int row  = blockIdx.x * 4 + wave;
  const float* src = f + (size_t)row * DD + lane * 8;
  float4 v0 = *(const float4*)src;
  float4 v1 = *(const float4*)(src + 4);
  float ss = v0.x*v0.x + v0.y*v0.y + v0.z*v0.z + v0.w*v0.w
           + v1.x*v1.x + v1.y*v1.y + v1.z*v1.z + v1.w*v1.w;
  #pragma unroll
  for (int o = 32; o; o >>= 1) ss += __shfl_xor(ss, o);
  const float r = 1.0f / fmaxf(sqrtf(ss), 1e-8f);
  ushort4 a, b;
  a.x = f32_to_bf16(v0.x * r); a.y = f32_to_bf16(v0.y * r);
  a.z = f32_to_bf16(v0.z * r); a.w = f32_to_bf16(v0.w * r);
  b.x = f32_to_bf16(v1.x * r); b.y = f32_to_bf16(v1.y * r);
  b.z = f32_to_bf16(v1.z * r); b.w = f32_to_bf16(v1.w * r);
  unsigned short* dst = fnb + (size_t)row * DD + lane * 8;
  *(ushort4*)dst = a;
  *(ushort4*)(dst + 4) = b;
}

// ---------------- Kernel B: single fused kernel ----------------
// 128x128 tile per block, 4 waves each 64x64 (4x4 of 16x16x32 bf16 MFMA).
// GEMM: coalesced async16 LDS staging. B-side uses R6's column permutation
// (tile nt, lane c16 -> fnb row J + wn*64 + 4*c16 + nt) realized via an LDS
// ROW permutation L(brow) = ((brow>>2)&31) | ((brow&3)<<5) at staging time,
// so epilogue lane c16 owns sim columns 4*c16..4*c16+3 == one int4 of mask.
// Epilogue: direct coalesced int4 mask loads (1KB/wave-instr) -> FMA ->
// shfl-reduce -> LDS accum (lgkmcnt; never stalls vmem) -> one batch of
// global atomics at the end (R7 lesson: atomics in the vmcnt chain poison
// every later load).
__global__ __launch_bounds__(256, 3) void fused_kernel(const unsigned short* __restrict__ fnb,
                                                       const int* __restrict__ posm,
                                                       const int* __restrict__ negm,
                                                       float* __restrict__ Spos,
                                                       float* __restrict__ Sneg,
                                                       float* __restrict__ Pcnt) {
  // decode compact triangular block id -> (bi, bj), bi <= bj, 64x64 block grid
  const int bid = blockIdx.x;
  int bi = (int)(64.5 - sqrt(64.5 * 64.5 - 2.0 * (double)bid));
  while (64 * bi - bi * (bi - 1) / 2 > bid) --bi;
  while (64 * (bi + 1) - (bi + 1) * bi / 2 <= bid) ++bi;
  const int bj = bi + (bid - (64 * bi - bi * (bi - 1) / 2));
  const int I = bi * 128;
  const int J = bj * 128;
  const bool offdiag = (bi != bj);

  const int tid  = threadIdx.x;
  const int wave = tid >> 6;
  const int lane = tid & 63;
  const int wm = wave >> 1;            // 0..1 row half
  const int wn = wave & 1;             // 0..1 col half
  const int q   = lane >> 4;           // 0..3
  const int c16 = lane & 15;           // 0..15

  __shared__ alignas(16) unsigned short lA[128 * 32];
  __shared__ alignas(16) unsigned short lB[128 * 32];
  __shared__ float sacc[2][128][3];    // [panel][row][Spos,Sneg,Pcnt]
  for (int t = tid; t < 2 * 128 * 3; t += 256) ((float*)sacc)[t] = 0.f;

  // ---- GEMM ----
  f32x4 acc[4][4];
  const f32x4 z4 = {0.f, 0.f, 0.f, 0.f};
  #pragma unroll
  for (int mt = 0; mt < 4; ++mt)
    #pragma unroll
    for (int nt = 0; nt < 4; ++nt) acc[mt][nt] = z4;

  for (int kk = 0; kk < DD / 32; ++kk) {
    const int k0 = kk * 32;
    #pragma unroll
    for (int c = 0; c < 2; ++c) {
      const int fidx = tid + c * 256;        // 0..511 16B-chunks
      const int L    = fidx >> 2;            // LDS row 0..127
      const int p    = fidx & 3;
      const int csrc = (p ^ ((L >> 1) & 3)) & 3;     // chunk XOR swizzle
      // lA: natural row order (R8-proven, 0 conflicts)
      async16(fnb + (size_t)(I + L) * DD + k0 + csrc * 8, (char*)lA + fidx * 16);
      // lB: row-permuted so MFMA B-reads (global row 4*c16+t) stay 2-way in banks
      const int gB = 4 * (L & 31) + (L >> 5);        // inverse of L(brow)
      async16(fnb + (size_t)(J + gB) * DD + k0 + csrc * 8, (char*)lB + fidx * 16);
    }
    __syncthreads();

    s16x8 aF[4], bF[4];
    #pragma unroll
    for (int t = 0; t < 4; ++t) {
      const int arow = wm * 64 + t * 16 + c16;
      const int apos = (q ^ ((arow >> 1) & 3)) & 3;
      aF[t] = *(const s16x8*)((const char*)lA + arow * 64 + apos * 16);
      // want global row brow = wn*64 + 4*c16 + t  ->  LDS row L(brow)
      const int Lb = (wn * 16 + c16) | (t << 5);
      const int bpos = (q ^ ((Lb >> 1) & 3)) & 3;
      bF[t] = *(const s16x8*)((const char*)lB + Lb * 64 + bpos * 16);
    }
    #pragma unroll
    for (int mt = 0; mt < 4; ++mt)
      #pragma unroll
      for (int nt = 0; nt < 4; ++nt)
        acc[mt][nt] = __builtin_amdgcn_mfma_f32_16x16x32_bf16(aF[mt], bF[nt], acc[mt][nt], 0, 0, 0);
    __syncthreads();
  }

  // ---- epilogue ----
  // acc[mt][nt][r] = sim[I + wm*64 + mt*16 + q*4 + r][J + wn*64 + 4*c16 + nt]
  #pragma unroll
  for (int mt = 0; mt < 4; ++mt)
    #pragma unroll
    for (int nt = 0; nt < 4; ++nt)
      #pragma unroll
      for (int r = 0; r < 4; ++r)
        acc[mt][nt][r] = __expf(acc[mt][nt][r] * INV_T - INV_T);

  const bool hasdiag = (bi == bj) && (wm == wn);
  const int cb = wn * 64 + 4 * c16;            // local col base (this lane's int4)

  // direct pass: rows I.., cols J.. ; 1KB/wave-instr coalesced int4 loads
  #pragma unroll
  for (int mt = 0; mt < 4; ++mt) {
    const int rl = wm * 64 + mt * 16 + q * 4;  // local row base
    i32x4 pv[4], nv[4];
    #pragma unroll
    for (int r = 0; r < 4; ++r) {
      const size_t off = (size_t)(I + rl + r) * NN + J + cb;
      pv[r] = __builtin_nontemporal_load((const i32x4*)(posm + off));
      nv[r] = __builtin_nontemporal_load((const i32x4*)(negm + off));
    }
    #pragma unroll
    for (int r = 0; r < 4; ++r) {
      float dsp = 0.f, dsn = 0.f, dpc = 0.f;
      #pragma unroll
      for (int nt = 0; nt < 4; ++nt) {
        float pf = (float)pv[r][nt];
        float nf = (float)nv[r][nt];
        if (hasdiag && (rl + r == cb + nt)) { pf = 0.f; nf = 0.f; }  // self-contrast diag
        const float e = acc[mt][nt][r];
        dsp = fmaf(e, pf, dsp);
        dsn = fmaf(e, nf, dsn);
        dpc += pf;
      }
      #pragma unroll
      for (int o = 1; o <= 8; o <<= 1) {
        dsp += __shfl_xor(dsp, o);
        dsn += __shfl_xor(dsn, o);
        dpc += __shfl_xor(dpc, o);
      }
      if (c16 == 0) {   // LDS atomics: lgkmcnt only
        atomicAdd(&sacc[0][rl + r][0], dsp);
        atomicAdd(&sacc[0][rl + r][1], dsn);
        atomicAdd(&sacc[0][rl + r][2], dpc);
      }
    }
  }

  // transposed pass: sim(col,row) == sim(row,col); rows J.., cols I..
  if (offdiag) {
    #pragma unroll
    for (int nt = 0; nt < 4; ++nt) {
      const int trl = cb + nt;                 // local row in J-panel
      i32x4 pv[4], nv[4];
      #pragma unroll
      for (int mt = 0; mt < 4; ++mt) {
        const size_t off = (size_t)(J + trl) * NN + I + wm * 64 + mt * 16 + q * 4;
        pv[mt] = __builtin_nontemporal_load((const i32x4*)(posm + off));
        nv[mt] = __builtin_nontemporal_load((const i32x4*)(negm + off));
      }
      float ts = 0.f, tn = 0.f, tp = 0.f;
      #pragma unroll
      for (int mt = 0; mt < 4; ++mt) {
        #pragma unroll
        for (int r = 0; r < 4; ++r) {
          const float e = acc[mt][nt][r];
          ts = fmaf(e, (float)pv[mt][r], ts);
          tn = fmaf(e, (float)nv[mt][r], tn);
          tp += (float)pv[mt][r];
        }
      }
      ts += __shfl_xor(ts, 16); ts += __shfl_xor(ts, 32);
      tn += __shfl_xor(tn, 16); tn += __shfl_xor(tn, 32);
      tp += __shfl_xor(tp, 16); tp += __shfl_xor(tp, 32);
      if (q == 0) {
        atomicAdd(&sacc[1][trl][0], ts);
        atomicAdd(&sacc[1][trl][1], tn);
        atomicAdd(&sacc[1][trl][2], tp);
      }
    }
  }

  __syncthreads();

  // one batch of global atomics at the very end; nothing waits on them
  const int r = tid & 127;
  if (tid < 128) {
    atomicAdd(&Spos[I + r], sacc[0][r][0]);
    atomicAdd(&Sneg[I + r], sacc[0][r][1]);
    atomicAdd(&Pcnt[I + r], sacc[0][r][2]);
  } else if (offdiag) {
    atomicAdd(&Spos[J + r], sacc[1][r][0]);
    atomicAdd(&Sneg[J + r], sacc[1][r][1]);
    atomicAdd(&Pcnt[J + r], sacc[1][r][2]);
  }
}

// ---------------- Kernel C: finalize ----------------
__global__ __launch_bounds__(256) void finalize_kernel(const float* __restrict__ Spos,
                                                       const float* __restrict__ Sneg,
                                                       const float* __restrict__ Pcnt,
                                                       float* __restrict__ out) {
  float local = 0.f;
  for (int i = threadIdx.x; i < NN; i += 256) {
    const float sp = Spos[i], sn = Sneg[i], pc = Pcnt[i];
    const float card = (pc == 0.f) ? 1.f : pc;
    local += (logf(sn) * pc - sp) / card;
  }
  #pragma unroll
  for (int o = 32; o; o >>= 1) local += __shfl_xor(local, o);
  __shared__ float red[4];
  if ((threadIdx.x & 63) == 0) red[threadIdx.x >> 6] = local;
  __syncthreads();
  if (threadIdx.x == 0)
    out[0] = (red[0] + red[1] + red[2] + red[3]) * (1.0f / (float)NN);
}

extern "C" void kernel_launch(void* const* d_in, const int* in_sizes, int n_in,
                              void* d_out, int out_size, void* d_ws, size_t ws_size,
                              hipStream_t stream) {
  const float* feat = (const float*)d_in[0];
  const int* posm   = (const int*)d_in[1];
  const int* negm   = (const int*)d_in[2];
  float* out = (float*)d_out;

  char* ws = (char*)d_ws;
  unsigned short* fnb = (unsigned short*)ws;                 // 8 MB
  float* Spos = (float*)(ws + (size_t)8 * 1024 * 1024);
  float* Sneg = Spos + NN;
  float* Pcnt = Sneg + NN;

  hipMemsetAsync(Spos, 0, 3 * NN * sizeof(float), stream);
  normalize_kernel<<<NN / 4, 256, 0, stream>>>(feat, fnb);
  fused_kernel<<<2080, 256, 0, stream>>>(fnb, posm, negm, Spos, Sneg, Pcnt);
  finalize_kernel<<<1, 256, 0, stream>>>(Spos, Sneg, Pcnt, out);
}